// Round 7
// baseline (105.910 us; speedup 1.0000x reference)
//
#include <hip/hip_runtime.h>

#define HH   48
#define WW   96
#define CC   256
#define RRAD 4
#define DD   9
#define DD2  81
#define PP   10
#define HWSZ (HH * WW)              // 4608
#define ROWB 512                    // bytes per bf16 channel row (256*2)
#define ZOFF ((unsigned)HWSZ * ROWB) // zero page offset from f2tb base

typedef __attribute__((ext_vector_type(8))) short short8v;  // 8 bf16 (4 VGPRs)
typedef __attribute__((ext_vector_type(4))) float f32x4;

__device__ __forceinline__ unsigned bf16rne(float f) {      // RNE f32->bf16 bits
  unsigned u = __float_as_uint(f);
  return (u + 0x7FFFu + ((u >> 16) & 1u)) >> 16;
}

// async global->LDS: LDS dest = wave-uniform base + lane*16 (linear), global src
// per-lane. Here src is CONTIGUOUS per 32-lane group -> TA lane-merge friendly.
__device__ __forceinline__ void gload_lds16(const char* g, char* l) {
  __builtin_amdgcn_global_load_lds(
      (const __attribute__((address_space(1))) char*)g,
      (__attribute__((address_space(3))) char*)l, 16, 0, 0);
}

// ---------------- kernel 1: (C,H,W) fp32 -> (H*W, 256ch) bf16, both inputs ----------------
__global__ __launch_bounds__(256) void transpose_to_bf16(
    const float* __restrict__ f1, const float* __restrict__ f2,
    char* __restrict__ f2tb, char* __restrict__ f1tb, char* __restrict__ zpage) {
  __shared__ float tile[64][65];
  const float* src = (blockIdx.y == 0) ? f1 : f2;
  char* dst = (blockIdx.y == 0) ? f1tb : f2tb;

  const int tid = threadIdx.x;
  if (blockIdx.y == 0 && blockIdx.x == 0 && tid < 32) {   // zero the 512 B zero page
    float4 z = {0.f, 0.f, 0.f, 0.f};
    *(float4*)(zpage + tid * 16) = z;
  }

  const int tiles_p = HWSZ / 64;              // 72
  const int bc = blockIdx.x / tiles_p;        // channel tile 0..3
  const int bp = blockIdx.x % tiles_p;        // pixel tile 0..71
  const int c0 = bc * 64, p0 = bp * 64;

#pragma unroll
  for (int k = 0; k < 16; k++) {
    int idx = k * 256 + tid;
    int cl = idx >> 6, pl = idx & 63;         // coalesced over pixels
    tile[cl][pl] = src[(size_t)(c0 + cl) * HWSZ + p0 + pl];
  }
  __syncthreads();
#pragma unroll
  for (int k = 0; k < 8; k++) {               // pack 2 channels -> 4 B stores
    int idx = k * 256 + tid;
    int pl = idx >> 5, cp = idx & 31;
    unsigned lo = bf16rne(tile[2 * cp][pl]);
    unsigned hi = bf16rne(tile[2 * cp + 1][pl]);
    *(unsigned*)(dst + (size_t)(p0 + pl) * ROWB + (size_t)c0 * 2 + cp * 4) =
        lo | (hi << 16);
  }
}

// ---------------- kernel 2: staged MFMA correlation -> corrs[p][81] ----------------
// LDS ~52 KB -> 3 blocks/CU; no DAP here (its w_dap gather was 6561 scattered
// addrs/block = the invariant ~20 us wall across R1-R6).
__global__ __launch_bounds__(256, 3) void corr_main(
    const char* __restrict__ f2tb, const char* __restrict__ f1tb,
    const float* __restrict__ coords, float* __restrict__ corrs_g) {
  __shared__ __align__(16) char patch[100 * ROWB];  // 51200 B, LINEAR layout
  __shared__ unsigned rowoff[100];            // source byte offset (ZOFF = zero page)
  __shared__ float dots[112];

  const int p = blockIdx.x;                   // pixel h*W+w
  const int tid = threadIdx.x;

  const float cx = coords[p];
  const float cy = coords[HWSZ + p];
  const float fxf = floorf(cx), fyf = floorf(cy);
  const float fx = cx - fxf, fy = cy - fyf;   // fractional weights shared by all 81 offsets
  const int xb = (int)fxf - RRAD;
  const int yb = (int)fyf - RRAD;

  if (tid < 100) {
    int yy = tid / 10, xx = tid - yy * 10;
    int gy = yb + yy, gx = xb + xx;
    rowoff[tid] = (gx >= 0 && gx < WW && gy >= 0 && gy < HH)
                      ? (unsigned)(gy * WW + gx) * ROWB : ZOFF;
  }

  const int lane = tid & 63, wid = tid >> 6;
  const int hi = lane >> 4, lo = lane & 15;

  // B fragments: f1 vector (same for all 16 cols); k = hi*8 + j within ktile kt
  const char* f1b = f1tb + (size_t)p * ROWB + hi * 16;
  short8v bfrag[8];
#pragma unroll
  for (int kt = 0; kt < 8; kt++) bfrag[kt] = *(const short8v*)(f1b + kt * 64);

  __syncthreads();                            // rowoff ready

  // stage 100 rows via global_load_lds; 2 rows per instr; source contiguous
  // per 32-lane half (512 B run) -> clean merge. LDS dest linear.
  {
    const int sub = lane >> 5;                // which of the 2 rows in this instr
    const int col = (lane & 31) * 16;         // byte within row
    for (int s = wid; s < 50; s += 4) {
      const int r = 2 * s + sub;
      gload_lds16(f2tb + rowoff[r] + col, &patch[s * 1024]);
    }
  }
  __syncthreads();                            // drains vmcnt (staging complete)

  // 7 m-tiles of 16 patch rows; A-fragments from linear LDS (b128, compile-time offsets)
#pragma unroll
  for (int mi = 0; mi < 2; mi++) {
    const int m = wid + mi * 4;
    if (m < 7) {
      int row = m * 16 + lo;
      row = row > 99 ? 99 : row;              // tile-6 tail: dup row, discarded
      const char* rp = patch + row * ROWB + hi * 16;
      short8v a[8];
#pragma unroll
      for (int kt = 0; kt < 8; kt++)
        a[kt] = *(const short8v*)(rp + kt * 64);
      f32x4 acc = {0.f, 0.f, 0.f, 0.f};
#pragma unroll
      for (int kt = 0; kt < 8; kt++)
        acc = __builtin_amdgcn_mfma_f32_16x16x32_bf16(a[kt], bfrag[kt], acc, 0, 0, 0);
      // D: col = lo, row = hi*4 + j; keep col 0 only
      if (lo == 0) {
        const int rb = m * 16 + hi * 4;
        dots[rb + 0] = acc[0];
        dots[rb + 1] = acc[1];
        dots[rb + 2] = acc[2];
        dots[rb + 3] = acc[3];
      }
    }
  }
  __syncthreads();

  // 81 bilinear combines -> corrs[p][81] (contiguous 324 B store burst)
  if (tid < DD2) {
    const int i = tid / DD, j = tid - i * DD;
    const float d00 = dots[j * PP + i];
    const float d01 = dots[j * PP + i + 1];
    const float d10 = dots[(j + 1) * PP + i];
    const float d11 = dots[(j + 1) * PP + i + 1];
    const float c = (1.f - fy) * ((1.f - fx) * d00 + fx * d01) +
                    fy * ((1.f - fx) * d10 + fx * d11);
    corrs_g[(size_t)p * DD2 + tid] = c * 0.0625f;   // 1/sqrt(256)
  }
}

// ---------------- kernel 3: DAP  out[o][p] = sum_d W[o][d] * corrs[p][d] ----------------
// W indices are loop-uniform -> scalar s_load path (SMEM pipe, no TA cost).
// 3 waves/block: wave w handles o in [w*27, w*27+27); 64 pixels per block.
__global__ __launch_bounds__(192, 4) void dap_kernel(
    const float* __restrict__ corrs_g, const float* __restrict__ w_dap,
    float* __restrict__ out) {
  const int lane = threadIdx.x & 63;
  const int w = threadIdx.x >> 6;             // 0..2
  const int p = blockIdx.x * 64 + lane;

  // 81 corr values into registers (20 x dwordx4 + 1 dword, contiguous per lane)
  float v[84];
  const float* cp = corrs_g + (size_t)p * DD2;
#pragma unroll
  for (int k = 0; k < 20; k++)
    *(float4*)&v[k * 4] = *(const float4*)(cp + k * 4);
  v[80] = cp[80];

  const int o0 = w * 27;
  for (int oi = 0; oi < 27; oi++) {
    const int o = o0 + oi;
    const float* wr = w_dap + (size_t)o * DD2;  // uniform per wave -> s_load
    float acc = 0.f;
#pragma unroll
    for (int d = 0; d < DD2; d++) acc += wr[d] * v[d];
    out[(size_t)o * HWSZ + p] = acc;          // coalesced over lanes
  }
}

extern "C" void kernel_launch(void* const* d_in, const int* in_sizes, int n_in,
                              void* d_out, int out_size, void* d_ws, size_t ws_size,
                              hipStream_t stream) {
  const float* f1     = (const float*)d_in[0];
  const float* f2     = (const float*)d_in[1];
  const float* coords = (const float*)d_in[2];
  const float* w_dap  = (const float*)d_in[3];
  float* out = (float*)d_out;

  // ws layout: [f2tb: HWSZ*512 B][zpage: 512 B][f1tb: HWSZ*512 B][corrs: HWSZ*81*4 B]
  char*  f2tb  = (char*)d_ws;
  char*  zpage = f2tb + (size_t)HWSZ * ROWB;
  char*  f1tb  = zpage + 512;
  float* corrs = (float*)(f1tb + (size_t)HWSZ * ROWB);

  dim3 tgrid((CC / 64) * (HWSZ / 64), 2);
  transpose_to_bf16<<<tgrid, 256, 0, stream>>>(f1, f2, f2tb, f1tb, zpage);

  corr_main<<<dim3(HWSZ), 256, 0, stream>>>(f2tb, f1tb, coords, corrs);

  dap_kernel<<<dim3(HWSZ / 64), 192, 0, stream>>>(corrs, w_dap, out);
}

// Round 8
// 49.658 us; speedup vs baseline: 2.1328x; 2.1328x over previous
//
#include <hip/hip_runtime.h>

#define HH   48
#define WW   96
#define CC   256
#define RRAD 4
#define DD   9
#define DD2  81
#define PP   10
#define HWSZ (HH * WW)              // 4608
#define ROWB 512                    // bytes per bf16 channel row (256*2)
#define ZOFF ((unsigned)HWSZ * ROWB) // zero page offset from f2tb base

typedef __attribute__((ext_vector_type(8))) short short8v;  // 8 bf16 (4 VGPRs)
typedef __attribute__((ext_vector_type(4))) float f32x4;

__device__ __forceinline__ unsigned bf16rne(float f) {      // RNE f32->bf16 bits
  unsigned u = __float_as_uint(f);
  return (u + 0x7FFFu + ((u >> 16) & 1u)) >> 16;
}

// async global->LDS: LDS dest = wave-uniform base + lane*16 (linear), global src
// per-lane. Src contiguous per 32-lane group -> TA lane-merge friendly.
__device__ __forceinline__ void gload_lds16(const char* g, char* l) {
  __builtin_amdgcn_global_load_lds(
      (const __attribute__((address_space(1))) char*)g,
      (__attribute__((address_space(3))) char*)l, 16, 0, 0);
}

// ---------------- kernel 1: (C,H,W) fp32 -> (H*W, 256ch) bf16, both inputs ----------------
__global__ __launch_bounds__(256) void transpose_to_bf16(
    const float* __restrict__ f1, const float* __restrict__ f2,
    char* __restrict__ f2tb, char* __restrict__ f1tb, char* __restrict__ zpage) {
  __shared__ float tile[64][65];
  const float* src = (blockIdx.y == 0) ? f1 : f2;
  char* dst = (blockIdx.y == 0) ? f1tb : f2tb;

  const int tid = threadIdx.x;
  if (blockIdx.y == 0 && blockIdx.x == 0 && tid < 32) {   // zero the 512 B zero page
    float4 z = {0.f, 0.f, 0.f, 0.f};
    *(float4*)(zpage + tid * 16) = z;
  }

  const int tiles_p = HWSZ / 64;              // 72
  const int bc = blockIdx.x / tiles_p;        // channel tile 0..3
  const int bp = blockIdx.x % tiles_p;        // pixel tile 0..71
  const int c0 = bc * 64, p0 = bp * 64;

#pragma unroll
  for (int k = 0; k < 16; k++) {
    int idx = k * 256 + tid;
    int cl = idx >> 6, pl = idx & 63;         // coalesced over pixels
    tile[cl][pl] = src[(size_t)(c0 + cl) * HWSZ + p0 + pl];
  }
  __syncthreads();
#pragma unroll
  for (int k = 0; k < 8; k++) {               // pack 2 channels -> 4 B stores
    int idx = k * 256 + tid;
    int pl = idx >> 5, cp = idx & 31;
    unsigned lo = bf16rne(tile[2 * cp][pl]);
    unsigned hi = bf16rne(tile[2 * cp + 1][pl]);
    *(unsigned*)(dst + (size_t)(p0 + pl) * ROWB + (size_t)c0 * 2 + cp * 4) =
        lo | (hi << 16);
  }
}

// ---------------- kernel 2: staged MFMA correlation -> corrs[p][81] ----------------
__global__ __launch_bounds__(256, 3) void corr_main(
    const char* __restrict__ f2tb, const char* __restrict__ f1tb,
    const float* __restrict__ coords, float* __restrict__ corrs_g) {
  __shared__ __align__(16) char patch[100 * ROWB];  // 51200 B, LINEAR layout
  __shared__ unsigned rowoff[100];            // source byte offset (ZOFF = zero page)
  __shared__ float dots[112];

  const int p = blockIdx.x;                   // pixel h*W+w
  const int tid = threadIdx.x;

  const float cx = coords[p];
  const float cy = coords[HWSZ + p];
  const float fxf = floorf(cx), fyf = floorf(cy);
  const float fx = cx - fxf, fy = cy - fyf;   // fractional weights shared by all 81 offsets
  const int xb = (int)fxf - RRAD;
  const int yb = (int)fyf - RRAD;

  if (tid < 100) {
    int yy = tid / 10, xx = tid - yy * 10;
    int gy = yb + yy, gx = xb + xx;
    rowoff[tid] = (gx >= 0 && gx < WW && gy >= 0 && gy < HH)
                      ? (unsigned)(gy * WW + gx) * ROWB : ZOFF;
  }

  const int lane = tid & 63, wid = tid >> 6;
  const int hi = lane >> 4, lo = lane & 15;

  // B fragments: f1 vector (same for all 16 cols); k = hi*8 + j within ktile kt
  const char* f1b = f1tb + (size_t)p * ROWB + hi * 16;
  short8v bfrag[8];
#pragma unroll
  for (int kt = 0; kt < 8; kt++) bfrag[kt] = *(const short8v*)(f1b + kt * 64);

  __syncthreads();                            // rowoff ready

  // stage 100 rows via global_load_lds; 2 rows per instr; source contiguous
  // per 32-lane half (512 B run). LDS dest linear.
  {
    const int sub = lane >> 5;                // which of the 2 rows in this instr
    const int col = (lane & 31) * 16;         // byte within row
    for (int s = wid; s < 50; s += 4) {
      const int r = 2 * s + sub;
      gload_lds16(f2tb + rowoff[r] + col, &patch[s * 1024]);
    }
  }
  __syncthreads();                            // drains vmcnt (staging complete)

  // 7 m-tiles of 16 patch rows; A-fragments from linear LDS
#pragma unroll
  for (int mi = 0; mi < 2; mi++) {
    const int m = wid + mi * 4;
    if (m < 7) {
      int row = m * 16 + lo;
      row = row > 99 ? 99 : row;              // tile-6 tail: dup row, discarded
      const char* rp = patch + row * ROWB + hi * 16;
      short8v a[8];
#pragma unroll
      for (int kt = 0; kt < 8; kt++)
        a[kt] = *(const short8v*)(rp + kt * 64);
      f32x4 acc = {0.f, 0.f, 0.f, 0.f};
#pragma unroll
      for (int kt = 0; kt < 8; kt++)
        acc = __builtin_amdgcn_mfma_f32_16x16x32_bf16(a[kt], bfrag[kt], acc, 0, 0, 0);
      // D: col = lo, row = hi*4 + j; keep col 0 only
      if (lo == 0) {
        const int rb = m * 16 + hi * 4;
        dots[rb + 0] = acc[0];
        dots[rb + 1] = acc[1];
        dots[rb + 2] = acc[2];
        dots[rb + 3] = acc[3];
      }
    }
  }
  __syncthreads();

  // 81 bilinear combines -> corrs[p][81] (contiguous store burst)
  if (tid < DD2) {
    const int i = tid / DD, j = tid - i * DD;
    const float d00 = dots[j * PP + i];
    const float d01 = dots[j * PP + i + 1];
    const float d10 = dots[(j + 1) * PP + i];
    const float d11 = dots[(j + 1) * PP + i + 1];
    const float c = (1.f - fy) * ((1.f - fx) * d00 + fx * d01) +
                    fy * ((1.f - fx) * d10 + fx * d11);
    corrs_g[(size_t)p * DD2 + tid] = c * 0.0625f;   // 1/sqrt(256)
  }
}

// ---------------- kernel 3: DAP  out[o][p] = sum_d W[o][d] * corrs[p][d] ----------------
// 512 thr / 64 px per block. Wave w owns o in [10w, 10w+10] (boundary o duplicated
// across waves -> bitwise-identical writes, benign). Corr chunk hoisted to REGISTERS
// (static indices only — R7's v[84] spilled to scratch: 9 MB spill writes in PMC).
// W rows via wave-uniform pointer (readfirstlane) -> s_load scalar path, no TA cost.
__global__ __launch_bounds__(512, 2) void dap_kernel(
    const float* __restrict__ corrs_g, const float* __restrict__ w_dap,
    float* __restrict__ out) {
  __shared__ float ct[64][84];                // stride 84 floats (16B-aligned rows)
  const int tid = threadIdx.x;
  const int p0 = blockIdx.x * 64;

  for (int i = tid; i < 64 * DD2; i += 512) { // coalesced global read
    int pl = i / DD2, d = i - pl * DD2;
    ct[pl][d] = corrs_g[(size_t)p0 * DD2 + i];
  }
  __syncthreads();

  const int w = __builtin_amdgcn_readfirstlane(tid >> 6);  // scalar wave id
  const int lane = tid & 63;
  const int o0 = w * 10;

  float acc[11];
#pragma unroll
  for (int i = 0; i < 11; i++) acc[i] = 0.f;

  // K chunks: {0..19, 20..39, 40..59, 60..80}
#pragma unroll
  for (int c = 0; c < 4; c++) {
    const int d0 = c * 20;
    float cr[21];
#pragma unroll
    for (int k = 0; k < 5; k++)
      *(float4*)&cr[k * 4] = *(const float4*)&ct[lane][d0 + k * 4];
    if (c == 3) cr[20] = ct[lane][80];
#pragma unroll
    for (int oi = 0; oi < 11; oi++) {
      const float* wr = w_dap + (size_t)(o0 + oi) * DD2 + d0;  // uniform -> s_load
      float a = acc[oi];
      if (c == 3) {
#pragma unroll
        for (int k = 0; k < 21; k++) a += wr[k] * cr[k];
      } else {
#pragma unroll
        for (int k = 0; k < 20; k++) a += wr[k] * cr[k];
      }
      acc[oi] = a;
    }
  }

#pragma unroll
  for (int oi = 0; oi < 11; oi++) {
    const int o = o0 + oi;                    // max 80
    out[(size_t)o * HWSZ + p0 + lane] = acc[oi];  // coalesced over lanes
  }
}

extern "C" void kernel_launch(void* const* d_in, const int* in_sizes, int n_in,
                              void* d_out, int out_size, void* d_ws, size_t ws_size,
                              hipStream_t stream) {
  const float* f1     = (const float*)d_in[0];
  const float* f2     = (const float*)d_in[1];
  const float* coords = (const float*)d_in[2];
  const float* w_dap  = (const float*)d_in[3];
  float* out = (float*)d_out;

  // ws layout: [f2tb: HWSZ*512 B][zpage: 512 B][f1tb: HWSZ*512 B][corrs: HWSZ*81*4 B]
  char*  f2tb  = (char*)d_ws;
  char*  zpage = f2tb + (size_t)HWSZ * ROWB;
  char*  f1tb  = zpage + 512;
  float* corrs = (float*)(f1tb + (size_t)HWSZ * ROWB);

  dim3 tgrid((CC / 64) * (HWSZ / 64), 2);
  transpose_to_bf16<<<tgrid, 256, 0, stream>>>(f1, f2, f2tb, f1tb, zpage);

  corr_main<<<dim3(HWSZ), 256, 0, stream>>>(f2tb, f1tb, coords, corrs);

  dap_kernel<<<dim3(HWSZ / 64), 512, 0, stream>>>(corrs, w_dap, out);
}

// Round 9
// 37.850 us; speedup vs baseline: 2.7981x; 1.3120x over previous
//
#include <hip/hip_runtime.h>

#define HH   48
#define WW   96
#define CC   256
#define RRAD 4
#define DD   9
#define DD2  81
#define PP   10
#define HWSZ (HH * WW)              // 4608
#define ROWB 512                    // bytes per bf16 channel row (256*2)
#define ZOFF ((unsigned)HWSZ * ROWB) // zero page offset from f2tb base

typedef __attribute__((ext_vector_type(8))) short short8v;  // 8 bf16 (4 VGPRs)
typedef __attribute__((ext_vector_type(4))) float f32x4;

__device__ __forceinline__ unsigned bf16rne(float f) {      // RNE f32->bf16 bits
  unsigned u = __float_as_uint(f);
  return (u + 0x7FFFu + ((u >> 16) & 1u)) >> 16;
}

// async global->LDS: LDS dest = wave-uniform base + lane*16 (linear), global src
// per-lane (here contiguous per 32-lane half -> TA lane-merge friendly).
__device__ __forceinline__ void gload_lds16(const char* g, char* l) {
  __builtin_amdgcn_global_load_lds(
      (const __attribute__((address_space(1))) char*)g,
      (__attribute__((address_space(3))) char*)l, 16, 0, 0);
}

// ---------------- kernel 1: transposes + W-prep ----------------
// y==0: f1 -> f1tb [pixel][256ch] bf16; blocks x<36 also pack W -> Wb (96x96 bf16,
//       zero-padded; W ~ I so bf16 diag error ~2^-9 -> out err ~0.01, within budget)
// y==1: f2 -> f2tb same layout, + zero page
__global__ __launch_bounds__(256) void transpose_to_bf16(
    const float* __restrict__ f1, const float* __restrict__ f2,
    const float* __restrict__ w_dap, char* __restrict__ f2tb,
    char* __restrict__ f1tb, char* __restrict__ zpage,
    unsigned short* __restrict__ Wb) {
  __shared__ float tile[64][65];
  const float* src = (blockIdx.y == 0) ? f1 : f2;
  char* dst = (blockIdx.y == 0) ? f1tb : f2tb;

  const int tid = threadIdx.x;
  if (blockIdx.y == 0 && blockIdx.x == 0 && tid < 32) {   // zero the 512 B zero page
    float4 z = {0.f, 0.f, 0.f, 0.f};
    *(float4*)(zpage + tid * 16) = z;
  }
  if (blockIdx.y == 0 && blockIdx.x < 36) {   // W-prep: 9216 elems over 36 blocks
    int gid = blockIdx.x * 256 + tid;
    int r = gid / 96, c = gid - r * 96;
    float v = (r < DD2 && c < DD2) ? w_dap[r * DD2 + c] : 0.f;
    Wb[gid] = (unsigned short)bf16rne(v);
  }

  const int tiles_p = HWSZ / 64;              // 72
  const int bc = blockIdx.x / tiles_p;        // channel tile 0..3
  const int bp = blockIdx.x % tiles_p;        // pixel tile 0..71
  const int c0 = bc * 64, p0 = bp * 64;

#pragma unroll
  for (int k = 0; k < 16; k++) {
    int idx = k * 256 + tid;
    int cl = idx >> 6, pl = idx & 63;         // coalesced over pixels
    tile[cl][pl] = src[(size_t)(c0 + cl) * HWSZ + p0 + pl];
  }
  __syncthreads();
#pragma unroll
  for (int k = 0; k < 8; k++) {               // pack 2 channels -> 4 B stores
    int idx = k * 256 + tid;
    int pl = idx >> 5, cp = idx & 31;
    unsigned lo = bf16rne(tile[2 * cp][pl]);
    unsigned hi = bf16rne(tile[2 * cp + 1][pl]);
    *(unsigned*)(dst + (size_t)(p0 + pl) * ROWB + (size_t)c0 * 2 + cp * 4) =
        lo | (hi << 16);
  }
}

// ---------------- kernel 2: staged MFMA correlation + MFMA DAP, one block/pixel ----------------
__global__ __launch_bounds__(256, 3) void corr_main(
    const char* __restrict__ f2tb, const char* __restrict__ f1tb,
    const float* __restrict__ coords, const unsigned short* __restrict__ Wb,
    float* __restrict__ out) {
  __shared__ __align__(16) char patch[100 * ROWB];  // 51200 B, XOR-swizzled
  __shared__ unsigned rowoff[100];            // source byte offset (ZOFF = zero page)
  __shared__ float dots[112];
  __shared__ __align__(16) unsigned short cb[96];   // bf16(corr), zero-padded

  const int p = blockIdx.x;                   // pixel h*W+w
  const int tid = threadIdx.x;

  const float cx = coords[p];
  const float cy = coords[HWSZ + p];
  const float fxf = floorf(cx), fyf = floorf(cy);
  const float fx = cx - fxf, fy = cy - fyf;   // fractional weights shared by all 81 offsets
  const int xb = (int)fxf - RRAD;
  const int yb = (int)fyf - RRAD;

  if (tid < 100) {
    int yy = tid / 10, xx = tid - yy * 10;
    int gy = yb + yy, gx = xb + xx;
    rowoff[tid] = (gx >= 0 && gx < WW && gy >= 0 && gy < HH)
                      ? (unsigned)(gy * WW + gx) * ROWB : ZOFF;
  }

  const int lane = tid & 63, wid = tid >> 6;
  const int hi = lane >> 4, lo = lane & 15;

  // B fragments: f1 vector (same for all 16 cols); k = hi*8 + j within ktile kt
  const char* f1b = f1tb + (size_t)p * ROWB + hi * 16;
  short8v bfrag[8];
#pragma unroll
  for (int kt = 0; kt < 8; kt++) bfrag[kt] = *(const short8v*)(f1b + kt * 64);

  __syncthreads();                            // rowoff ready

  // stage 100 rows via global_load_lds; LDS dest linear; bank-swizzle by
  // PRE-SWIZZLING the global source: LDS[r][x] = G[r][x ^ ((r&7)<<4)]
  {
    const int sub = lane >> 5;                // which of the 2 rows in this instr
    const int col = (lane & 31) * 16;         // byte within row
    for (int s = wid; s < 50; s += 4) {
      const int r = 2 * s + sub;
      gload_lds16(f2tb + rowoff[r] + (col ^ ((r & 7) << 4)), &patch[s * 1024]);
    }
  }
  __syncthreads();                            // drains vmcnt (staging complete)

  // 7 m-tiles of 16 patch rows; A-fragments via swizzled ds_read_b128
  // (linear reads at 512B stride were a 16-way bank conflict)
#pragma unroll
  for (int mi = 0; mi < 2; mi++) {
    const int m = wid + mi * 4;
    if (m < 7) {
      int row = m * 16 + lo;
      row = row > 99 ? 99 : row;              // tile-6 tail: dup row, discarded
      const char* rp = patch + row * ROWB;
      const int swz = (row & 7) << 4;
      short8v a[8];
#pragma unroll
      for (int kt = 0; kt < 8; kt++)
        a[kt] = *(const short8v*)(rp + ((hi * 16 + kt * 64) ^ swz));
      f32x4 acc = {0.f, 0.f, 0.f, 0.f};
#pragma unroll
      for (int kt = 0; kt < 8; kt++)
        acc = __builtin_amdgcn_mfma_f32_16x16x32_bf16(a[kt], bfrag[kt], acc, 0, 0, 0);
      // D: col = lo, row = hi*4 + j; keep col 0 only
      if (lo == 0) {
        const int rb = m * 16 + hi * 4;
        dots[rb + 0] = acc[0];
        dots[rb + 1] = acc[1];
        dots[rb + 2] = acc[2];
        dots[rb + 3] = acc[3];
      }
    }
  }
  __syncthreads();

  // 81 bilinear combines -> cb[96] bf16 (zero-padded)
  if (tid < 96) {
    float c = 0.f;
    if (tid < DD2) {
      const int i = tid / DD, j = tid - i * DD;
      const float d00 = dots[j * PP + i];
      const float d01 = dots[j * PP + i + 1];
      const float d10 = dots[(j + 1) * PP + i];
      const float d11 = dots[(j + 1) * PP + i + 1];
      c = ((1.f - fy) * ((1.f - fx) * d00 + fx * d01) +
           fy * ((1.f - fx) * d10 + fx * d11)) * 0.0625f;   // 1/sqrt(256)
    }
    cb[tid] = (unsigned short)bf16rne(c);
  }
  __syncthreads();

  // DAP via MFMA: out96 = Wb(96x96) . cb ; Wb is L1-resident (18.4 KB, shared
  // by all blocks). B-frag broadcasts cb across all 16 cols; store col 0.
  short8v bq[3];
#pragma unroll
  for (int kt = 0; kt < 3; kt++)
    bq[kt] = *(const short8v*)&cb[kt * 32 + hi * 8];
#pragma unroll
  for (int mi = 0; mi < 2; mi++) {
    const int m = wid + mi * 4;
    if (m < 6) {
      const unsigned short* wr = Wb + (m * 16 + lo) * 96 + hi * 8;
      f32x4 acc = {0.f, 0.f, 0.f, 0.f};
#pragma unroll
      for (int kt = 0; kt < 3; kt++) {
        short8v aw = *(const short8v*)(wr + kt * 32);
        acc = __builtin_amdgcn_mfma_f32_16x16x32_bf16(aw, bq[kt], acc, 0, 0, 0);
      }
      if (lo == 0) {
#pragma unroll
        for (int j = 0; j < 4; j++) {
          const int o = m * 16 + hi * 4 + j;
          if (o < DD2) out[(size_t)o * HWSZ + p] = acc[j];
        }
      }
    }
  }
}

extern "C" void kernel_launch(void* const* d_in, const int* in_sizes, int n_in,
                              void* d_out, int out_size, void* d_ws, size_t ws_size,
                              hipStream_t stream) {
  const float* f1     = (const float*)d_in[0];
  const float* f2     = (const float*)d_in[1];
  const float* coords = (const float*)d_in[2];
  const float* w_dap  = (const float*)d_in[3];
  float* out = (float*)d_out;

  // ws layout: [f2tb: HWSZ*512][zpage: 512][f1tb: HWSZ*512][Wb: 96*96*2]
  char* f2tb  = (char*)d_ws;
  char* zpage = f2tb + (size_t)HWSZ * ROWB;
  char* f1tb  = zpage + 512;
  unsigned short* Wb = (unsigned short*)(f1tb + (size_t)HWSZ * ROWB);

  dim3 tgrid((CC / 64) * (HWSZ / 64), 2);
  transpose_to_bf16<<<tgrid, 256, 0, stream>>>(f1, f2, w_dap, f2tb, f1tb, zpage, Wb);

  corr_main<<<dim3(HWSZ), 256, 0, stream>>>(f2tb, f1tb, coords, Wb, out);
}

// Round 10
// 36.292 us; speedup vs baseline: 2.9183x; 1.0429x over previous
//
#include <hip/hip_runtime.h>

#define HH   48
#define WW   96
#define CC   256
#define RRAD 4
#define DD   9
#define DD2  81
#define PP   10
#define HWSZ (HH * WW)              // 4608
#define ROWB 512                    // bytes per bf16 channel row (256*2)
#define ZOFF ((unsigned)HWSZ * ROWB) // zero page offset from f2tb base

typedef __attribute__((ext_vector_type(8))) short short8v;  // 8 bf16 (4 VGPRs)
typedef __attribute__((ext_vector_type(4))) float f32x4;

__device__ __forceinline__ unsigned bf16rne(float f) {      // RNE f32->bf16 bits
  unsigned u = __float_as_uint(f);
  return (u + 0x7FFFu + ((u >> 16) & 1u)) >> 16;
}

// async global->LDS: LDS dest = wave-uniform base + lane*16 (linear), global src
// per-lane (here contiguous per 32-lane half -> TA lane-merge friendly).
__device__ __forceinline__ void gload_lds16(const char* g, char* l) {
  __builtin_amdgcn_global_load_lds(
      (const __attribute__((address_space(1))) char*)g,
      (__attribute__((address_space(3))) char*)l, 16, 0, 0);
}

// ---------------- kernel 1: transposes + W-prep (fragment-major) ----------------
// y==0: f1 -> f1tb [pixel][256ch] bf16; blocks x<36 also pack W into Wf in MFMA
//   FRAGMENT-MAJOR order: Wf[((m*3+kt)*64 + lane)*8 + e] = bf16(W[r][c]),
//   r = m*16+(lane&15), c = kt*32+(lane>>4)*8+e  (zero-padded past 81).
//   -> corr_main's DAP A-load is 1KB CONTIGUOUS per wave (R9's row-major Wb
//   gather touched ~64 lines/instr = ~9us of TA serialization).
// y==1: f2 -> f2tb same layout, + zero page
__global__ __launch_bounds__(256) void transpose_to_bf16(
    const float* __restrict__ f1, const float* __restrict__ f2,
    const float* __restrict__ w_dap, char* __restrict__ f2tb,
    char* __restrict__ f1tb, char* __restrict__ zpage,
    unsigned short* __restrict__ Wf) {
  __shared__ float tile[64][65];
  const float* src = (blockIdx.y == 0) ? f1 : f2;
  char* dst = (blockIdx.y == 0) ? f1tb : f2tb;

  const int tid = threadIdx.x;
  if (blockIdx.y == 0 && blockIdx.x == 0 && tid < 32) {   // zero the 512 B zero page
    float4 z = {0.f, 0.f, 0.f, 0.f};
    *(float4*)(zpage + tid * 16) = z;
  }
  if (blockIdx.y == 0 && blockIdx.x < 36) {   // W-prep: 9216 shorts over 36 blocks
    int gid = blockIdx.x * 256 + tid;
    int g = gid >> 9;                         // (m,kt) group 0..17
    int idx = gid & 511;
    int ln = idx >> 3, e = idx & 7;
    int m = g / 3, kt = g - m * 3;
    int r = m * 16 + (ln & 15);
    int c = kt * 32 + (ln >> 4) * 8 + e;
    float v = (r < DD2 && c < DD2) ? w_dap[r * DD2 + c] : 0.f;
    Wf[gid] = (unsigned short)bf16rne(v);
  }

  const int tiles_p = HWSZ / 64;              // 72
  const int bc = blockIdx.x / tiles_p;        // channel tile 0..3
  const int bp = blockIdx.x % tiles_p;        // pixel tile 0..71
  const int c0 = bc * 64, p0 = bp * 64;

#pragma unroll
  for (int k = 0; k < 16; k++) {
    int idx = k * 256 + tid;
    int cl = idx >> 6, pl = idx & 63;         // coalesced over pixels
    tile[cl][pl] = src[(size_t)(c0 + cl) * HWSZ + p0 + pl];
  }
  __syncthreads();
#pragma unroll
  for (int k = 0; k < 8; k++) {               // pack 2 channels -> 4 B stores
    int idx = k * 256 + tid;
    int pl = idx >> 5, cp = idx & 31;
    unsigned lo = bf16rne(tile[2 * cp][pl]);
    unsigned hi = bf16rne(tile[2 * cp + 1][pl]);
    *(unsigned*)(dst + (size_t)(p0 + pl) * ROWB + (size_t)c0 * 2 + cp * 4) =
        lo | (hi << 16);
  }
}

// ---------------- kernel 2: staged MFMA correlation + MFMA DAP, one block/pixel ----------------
__global__ __launch_bounds__(256, 3) void corr_main(
    const char* __restrict__ f2tb, const char* __restrict__ f1tb,
    const float* __restrict__ coords, const unsigned short* __restrict__ Wf,
    float* __restrict__ out) {
  __shared__ __align__(16) char patch[100 * ROWB];  // 51200 B, XOR-swizzled
  __shared__ unsigned rowoff[100];            // source byte offset (ZOFF = zero page)
  __shared__ float dots[112];
  __shared__ __align__(16) unsigned short cb[96];   // bf16(corr), zero-padded

  const int p = blockIdx.x;                   // pixel h*W+w
  const int tid = threadIdx.x;

  const float cx = coords[p];
  const float cy = coords[HWSZ + p];
  const float fxf = floorf(cx), fyf = floorf(cy);
  const float fx = cx - fxf, fy = cy - fyf;   // fractional weights shared by all 81 offsets
  const int xb = (int)fxf - RRAD;
  const int yb = (int)fyf - RRAD;

  if (tid < 100) {
    int yy = tid / 10, xx = tid - yy * 10;
    int gy = yb + yy, gx = xb + xx;
    rowoff[tid] = (gx >= 0 && gx < WW && gy >= 0 && gy < HH)
                      ? (unsigned)(gy * WW + gx) * ROWB : ZOFF;
  }

  const int lane = tid & 63, wid = tid >> 6;
  const int hi = lane >> 4, lo = lane & 15;

  // B fragments: f1 vector (same for all 16 cols); k = hi*8 + j within ktile kt
  const char* f1b = f1tb + (size_t)p * ROWB + hi * 16;
  short8v bfrag[8];
#pragma unroll
  for (int kt = 0; kt < 8; kt++) bfrag[kt] = *(const short8v*)(f1b + kt * 64);

  __syncthreads();                            // rowoff ready

  // stage 100 rows via global_load_lds; LDS dest linear; bank-swizzle by
  // PRE-SWIZZLING the global source: LDS[r][x] = G[r][x ^ ((r&7)<<4)]
  {
    const int sub = lane >> 5;                // which of the 2 rows in this instr
    const int col = (lane & 31) * 16;         // byte within row
    for (int s = wid; s < 50; s += 4) {
      const int r = 2 * s + sub;
      gload_lds16(f2tb + rowoff[r] + (col ^ ((r & 7) << 4)), &patch[s * 1024]);
    }
  }
  __syncthreads();                            // drains vmcnt (staging complete)

  // 7 m-tiles of 16 patch rows; A-fragments via swizzled ds_read_b128
#pragma unroll
  for (int mi = 0; mi < 2; mi++) {
    const int m = wid + mi * 4;
    if (m < 7) {
      int row = m * 16 + lo;
      row = row > 99 ? 99 : row;              // tile-6 tail: dup row, discarded
      const char* rp = patch + row * ROWB;
      const int swz = (row & 7) << 4;
      short8v a[8];
#pragma unroll
      for (int kt = 0; kt < 8; kt++)
        a[kt] = *(const short8v*)(rp + ((hi * 16 + kt * 64) ^ swz));
      f32x4 acc = {0.f, 0.f, 0.f, 0.f};
#pragma unroll
      for (int kt = 0; kt < 8; kt++)
        acc = __builtin_amdgcn_mfma_f32_16x16x32_bf16(a[kt], bfrag[kt], acc, 0, 0, 0);
      // D: col = lo, row = hi*4 + j; keep col 0 only
      if (lo == 0) {
        const int rb = m * 16 + hi * 4;
        dots[rb + 0] = acc[0];
        dots[rb + 1] = acc[1];
        dots[rb + 2] = acc[2];
        dots[rb + 3] = acc[3];
      }
    }
  }
  __syncthreads();

  // 81 bilinear combines -> cb[96] bf16 (zero-padded)
  if (tid < 96) {
    float c = 0.f;
    if (tid < DD2) {
      const int i = tid / DD, j = tid - i * DD;
      const float d00 = dots[j * PP + i];
      const float d01 = dots[j * PP + i + 1];
      const float d10 = dots[(j + 1) * PP + i];
      const float d11 = dots[(j + 1) * PP + i + 1];
      c = ((1.f - fy) * ((1.f - fx) * d00 + fx * d01) +
           fy * ((1.f - fx) * d10 + fx * d11)) * 0.0625f;   // 1/sqrt(256)
    }
    cb[tid] = (unsigned short)bf16rne(c);
  }
  __syncthreads();

  // DAP via MFMA: out96 = W(96x96) . cb. A-fragments from Wf (fragment-major,
  // 1KB contiguous per wave-load, L1-resident). Store col 0.
  short8v bq[3];
#pragma unroll
  for (int kt = 0; kt < 3; kt++)
    bq[kt] = *(const short8v*)&cb[kt * 32 + hi * 8];
#pragma unroll
  for (int mi = 0; mi < 2; mi++) {
    const int m = wid + mi * 4;
    if (m < 6) {
      const unsigned short* wr = Wf + ((size_t)(m * 3) * 64 + lane) * 8;
      f32x4 acc = {0.f, 0.f, 0.f, 0.f};
#pragma unroll
      for (int kt = 0; kt < 3; kt++) {
        short8v aw = *(const short8v*)(wr + (size_t)kt * 512);
        acc = __builtin_amdgcn_mfma_f32_16x16x32_bf16(aw, bq[kt], acc, 0, 0, 0);
      }
      if (lo == 0) {
#pragma unroll
        for (int j = 0; j < 4; j++) {
          const int o = m * 16 + hi * 4 + j;
          if (o < DD2) out[(size_t)o * HWSZ + p] = acc[j];
        }
      }
    }
  }
}

extern "C" void kernel_launch(void* const* d_in, const int* in_sizes, int n_in,
                              void* d_out, int out_size, void* d_ws, size_t ws_size,
                              hipStream_t stream) {
  const float* f1     = (const float*)d_in[0];
  const float* f2     = (const float*)d_in[1];
  const float* coords = (const float*)d_in[2];
  const float* w_dap  = (const float*)d_in[3];
  float* out = (float*)d_out;

  // ws layout: [f2tb: HWSZ*512][zpage: 512][f1tb: HWSZ*512][Wf: 9216*2]
  char* f2tb  = (char*)d_ws;
  char* zpage = f2tb + (size_t)HWSZ * ROWB;
  char* f1tb  = zpage + 512;
  unsigned short* Wf = (unsigned short*)(f1tb + (size_t)HWSZ * ROWB);

  dim3 tgrid((CC / 64) * (HWSZ / 64), 2);
  transpose_to_bf16<<<tgrid, 256, 0, stream>>>(f1, f2, w_dap, f2tb, f1tb, zpage, Wf);

  corr_main<<<dim3(HWSZ), 256, 0, stream>>>(f2tb, f1tb, coords, Wf, out);
}